// Round 23
// baseline (712.461 us; speedup 1.0000x reference)
//
#include <hip/hip_runtime.h>

// HNN structure embed (N=3, HID=1024, bs=32768).
// GEMMs: bf16 MFMA 16x16x32, 128x128x64 tiles, 2-slot LDS ring (64 KB),
// minimal 2-phase loop, __launch_bounds__(256,2), in-place EPI1 aliasing.
// R23 = R22 minus the per-kk sched_barrier(0) in COMPUTE: with natural
// VGPR at 88 (40 regs headroom under the forced-128 cap) the scheduler may
// now interleave kk=1's ds_reads among kk=0's MFMAs to hide LDS latency.
// Gate: FETCH/WRITE must stay clean (inflation = spill = revert).
// MFMA-based fused reductions + sumP collapse unchanged from R21/R22.
// Per-row 3x3 algebra in f32. dHdp == q_dot (exact). V layer-3 fwd skipped.

#define HID 1024
#define BS  32768

typedef __attribute__((ext_vector_type(8))) short short8;
typedef __attribute__((ext_vector_type(4))) float f32x4;
typedef __attribute__((ext_vector_type(8))) unsigned short ushort8v;
typedef __attribute__((ext_vector_type(4))) unsigned short ushort4v;

typedef __attribute__((address_space(1))) const char gconst_char;
typedef __attribute__((address_space(3))) char lds_char;

__device__ __forceinline__ unsigned short f2bf(float f) {
  unsigned int u = __builtin_bit_cast(unsigned int, f);
  u += 0x7fffu + ((u >> 16) & 1u);   // RNE
  return (unsigned short)(u >> 16);
}
__device__ __forceinline__ float bf2f(unsigned short s) {
  unsigned int u = ((unsigned int)s) << 16;
  return __builtin_bit_cast(float, u);
}
__device__ __forceinline__ float tanh_fast(float x) {
  float e = __builtin_amdgcn_exp2f(x * 2.885390081777927f); // e^(2x)
  return 1.f - 2.f * __builtin_amdgcn_rcpf(e + 1.f);
}

// ---------------- weight packing: pT[n][k]=bf16(W[k][n]); pC[n][k]=bf16(W[n][k])
__global__ __launch_bounds__(256) void pack_w(const float* __restrict__ W,
                                              unsigned short* __restrict__ pT,
                                              unsigned short* __restrict__ pC) {
  __shared__ float tile[64][65];
  int b = blockIdx.x;
  int k0 = (b >> 4) << 6;
  int n0 = (b & 15) << 6;
  int t = threadIdx.x;
  for (int i = 0; i < 16; ++i) {
    int idx = i * 256 + t;
    int r = idx >> 6, c = idx & 63;
    tile[r][c] = W[(size_t)(k0 + r) * HID + n0 + c];
  }
  if (pC) {
    for (int i = 0; i < 16; ++i) {
      int idx = i * 256 + t;
      int r = idx >> 6, c = idx & 63;
      pC[(size_t)(n0 + r) * HID + k0 + c] = f2bf(W[(size_t)(n0 + r) * HID + k0 + c]);
    }
  }
  __syncthreads();
  for (int i = 0; i < 16; ++i) {
    int idx = i * 256 + t;
    int n = idx >> 6, k = idx & 63;
    pT[(size_t)(n0 + n) * HID + k0 + k] = f2bf(tile[k][n]);
  }
}

// ---------------- partial-sum collapse: out[idx] = sum_nt Pp[nt][idx] (+bias)
template<int KR>
__global__ __launch_bounds__(256) void sumP(const float* __restrict__ Pp,
                                            const float* __restrict__ bias,
                                            float* __restrict__ outv) {
  int idx = blockIdx.x * 256 + threadIdx.x;   // over BS*KR
  float sv = 0.f;
  #pragma unroll
  for (int nt = 0; nt < 8; ++nt) sv += Pp[(size_t)nt * BS * KR + idx];
  if (bias) {
    int j = idx - (idx / KR) * KR;
    sv += bias[j];
  }
  outv[idx] = sv;
}

// ---------------- big GEMM: C[m][n] = epi( sum_k A[m][k]*Bp[n][k] )
// EPI 0: tanh(acc + bias[col])
// EPI 1: acc * (1 - bf2f(aux[row][col])^2)  (aux = bf16 tanh act; may alias C)
// EPI 2: w3[col] * (1 - tanh(acc + bias[col])^2)   (fused mapV)
// KRED>0: fused reduction red[row][j] = sum_col epi_val[row][col]*W[col][j],
//   computed via MFMA from the LDS C tile; partials stored race-free to
//   redOut[(nt*BS + r0+row)*KRED + j].
//   KRED==6: redW layout [6][1024];  KRED==3/9: redW layout [1024][KRED].
// SKIPC: skip global C store (output consumed only by the reduction).
template<int EPI, int KRED, bool SKIPC>
__global__ __launch_bounds__(256, 2) void gemm_bf16(
    const unsigned short* __restrict__ A,
    const unsigned short* __restrict__ Bp,
    unsigned short* __restrict__ C,
    const float* __restrict__ bias,
    const unsigned short* __restrict__ aux,
    const float* __restrict__ w3,
    const float* __restrict__ redW,
    float* __restrict__ redOut)
{
  __shared__ __align__(1024) char lds[65536];   // 2 x (A 16K + B 16K)
  const int t = threadIdx.x;
  const int w = t >> 6, l = t & 63;
  // bijective XCD swizzle: 2048 blocks, 8 XCDs -> each XCD owns 32 M-panels
  int bid = (int)blockIdx.x;
  int wg  = (bid & 7) * 256 + (bid >> 3);
  const int nt = wg & 7, mt = wg >> 3;
  const int r0 = mt << 7, n0 = nt << 7;
  const int wr = w >> 1, wc = w & 1;

  f32x4 acc[4][4] = {};
  const int lbase = (w << 2);

  const char* Abase = (const char*)A  + ((size_t)r0 << 11);
  const char* Bbase = (const char*)Bp + ((size_t)n0 << 11);

  auto STAGE = [&](char* Ad, int kt) {
    char* Bd = Ad + 16384;
    const char* Ak = Abase + kt * 128;
    const char* Bk = Bbase + kt * 128;
    #pragma unroll
    for (int i = 0; i < 4; ++i) {
      int o   = ((lbase + i) << 10) + (l << 4);
      int row = o >> 7;
      int vo  = (row << 11) + ((o & 127) ^ ((row & 7) << 4));   // inv swizzle on SOURCE
      __builtin_amdgcn_global_load_lds((gconst_char*)(Ak + vo), (lds_char*)(Ad + ((lbase + i) << 10)), 16, 0, 0);
      __builtin_amdgcn_global_load_lds((gconst_char*)(Bk + vo), (lds_char*)(Bd + ((lbase + i) << 10)), 16, 0, 0);
    }
  };

  auto COMPUTE = [&](const char* As) {
    const char* Bs = As + 16384;
    #pragma unroll
    for (int kk = 0; kk < 2; ++kk) {
      short8 bfr[4];
      #pragma unroll
      for (int n = 0; n < 4; ++n) {
        int col = (wc << 6) + (n << 4) + (l & 15);
        int off = (col << 7) + ((l >> 4) << 4) + (kk << 6);
        off ^= ((col & 7) << 4);
        bfr[n] = *(const short8*)(Bs + off);
      }
      #pragma unroll
      for (int m = 0; m < 4; ++m) {
        int row = (wr << 6) + (m << 4) + (l & 15);
        int off = (row << 7) + ((l >> 4) << 4) + (kk << 6);
        off ^= ((row & 7) << 4);
        short8 af = *(const short8*)(As + off);
        #pragma unroll
        for (int n = 0; n < 4; ++n) {
          acc[m][n] = __builtin_amdgcn_mfma_f32_16x16x32_bf16(af, bfr[n], acc[m][n], 0, 0, 0);
        }
      }
    }
  };

  char* L0 = lds;
  char* L1 = lds + 32768;

  // prologue: tile 0 into L0, drain, sync
  STAGE(L0, 0);
  asm volatile("s_waitcnt vmcnt(0)" ::: "memory");
  __builtin_amdgcn_s_barrier();

  // minimal 2-phase: STAGE(next) -> COMPUTE(cur) -> vmcnt(0) -> barrier.
  #pragma unroll 1
  for (int kt2 = 0; kt2 < 7; ++kt2) {
    STAGE(L1, 2 * kt2 + 1);
    COMPUTE(L0);
    asm volatile("s_waitcnt vmcnt(0)" ::: "memory");
    __builtin_amdgcn_s_barrier();
    STAGE(L0, 2 * kt2 + 2);
    COMPUTE(L1);
    asm volatile("s_waitcnt vmcnt(0)" ::: "memory");
    __builtin_amdgcn_s_barrier();
  }
  STAGE(L1, 15);
  COMPUTE(L0);
  asm volatile("s_waitcnt vmcnt(0)" ::: "memory");
  __builtin_amdgcn_s_barrier();
  COMPUTE(L1);
  __syncthreads();   // ds_reads retired before epilogue reuses LDS

  // stage reduction weights as bf16 wjk[j=0..15][col=0..127], 272B rows
  // (j >= KRED rows zeroed). B-frag reads are 16B contiguous per lane.
  char* wjk = lds + 32768;
  if (KRED == 9) {
    int col = t >> 1;
    if ((t & 1) == 0) {
      #pragma unroll
      for (int j = 0; j < 8; ++j) {
        float v = redW[(size_t)(n0 + col) * 9 + j];
        *(unsigned short*)(wjk + j * 272 + col * 2) = f2bf(v);
      }
    } else {
      #pragma unroll
      for (int j = 8; j < 16; ++j) {
        float v = (j == 8) ? redW[(size_t)(n0 + col) * 9 + 8] : 0.f;
        *(unsigned short*)(wjk + j * 272 + col * 2) = f2bf(v);
      }
    }
  } else if (KRED == 3) {
    int col = t >> 1;
    if ((t & 1) == 0) {
      #pragma unroll
      for (int j = 0; j < 8; ++j) {
        float v = (j < 3) ? redW[(size_t)(n0 + col) * 3 + j] : 0.f;
        *(unsigned short*)(wjk + j * 272 + col * 2) = f2bf(v);
      }
    } else {
      #pragma unroll
      for (int j = 8; j < 16; ++j) {
        *(unsigned short*)(wjk + j * 272 + col * 2) = 0;
      }
    }
  } else if (KRED == 6) {
    int col = t & 127;
    #pragma unroll
    for (int it = 0; it < 8; ++it) {
      int j = it * 2 + (t >> 7);
      float v = (j < 6) ? redW[(size_t)j * HID + n0 + col] : 0.f;
      *(unsigned short*)(wjk + j * 272 + col * 2) = f2bf(v);
    }
  }

  // epilogue: apply epi, stage bf16 tile in LDS (swizzled)
  char* Cs = lds;
  #pragma unroll
  for (int n = 0; n < 4; ++n) {
    const int colL = (wc << 6) + (n << 4) + (l & 15);
    const int gcol = n0 + colL;
    float bval = 0.f, w3v = 0.f;
    if (EPI == 0 || EPI == 2) bval = bias[gcol];
    if (EPI == 2) w3v = w3[gcol];
    #pragma unroll
    for (int m = 0; m < 4; ++m) {
      #pragma unroll
      for (int r = 0; r < 4; ++r) {
        const int rowL = (wr << 6) + (m << 4) + ((l >> 4) << 2) + r;
        float v = acc[m][n][r];
        if (EPI == 0) {
          v = tanh_fast(v + bval);
        } else if (EPI == 1) {
          float h = bf2f(aux[((size_t)(r0 + rowL) << 10) + gcol]);
          v *= (1.f - h * h);
        } else {
          float th = tanh_fast(v + bval);
          v = w3v * (1.f - th * th);
        }
        int so = (rowL << 8) + (colL << 1);
        so ^= ((rowL & 7) << 5);
        *(unsigned short*)(Cs + so) = f2bf(v);
      }
      __builtin_amdgcn_sched_barrier(0);   // cap live acc reads per chunk
    }
  }
  __syncthreads();   // all aux reads + Cs/wjk writes done

  // optional global C store (coalesced from swizzled LDS tile)
  if (!SKIPC) {
    #pragma unroll
    for (int j = 0; j < 8; ++j) {
      int o    = (j << 12) + (t << 4);
      int rowL = o >> 8;
      int ir   = o & 255;
      uint4 v = *(const uint4*)(Cs + ((rowL << 8) + (ir ^ ((rowL & 7) << 5))));
      *(uint4*)(C + ((size_t)(r0 + rowL) << 10) + n0 + (ir >> 1)) = v;
      __builtin_amdgcn_sched_barrier(0);  // cap store live set
    }
  }

  // fused reduction via MFMA: red[row][j] = sum_col Cs[row][col]*wjk[j][col].
  // Wave w covers rows w*32..w*32+31 (2 m-frags), K=128 in 4 steps.
  if (KRED > 0) {
    f32x4 racc0 = {0.f, 0.f, 0.f, 0.f};
    f32x4 racc1 = {0.f, 0.f, 0.f, 0.f};
    #pragma unroll
    for (int kt = 0; kt < 4; ++kt) {
      short8 bfr = *(const short8*)(wjk + (l & 15) * 272 + (kt << 6) + ((l >> 4) << 4));
      {
        int row = (w << 5) + (l & 15);
        int off = (row << 8) + (kt << 6) + ((l >> 4) << 4);
        off ^= ((row & 7) << 5);
        short8 af = *(const short8*)(Cs + off);
        racc0 = __builtin_amdgcn_mfma_f32_16x16x32_bf16(af, bfr, racc0, 0, 0, 0);
      }
      {
        int row = (w << 5) + 16 + (l & 15);
        int off = (row << 8) + (kt << 6) + ((l >> 4) << 4);
        off ^= ((row & 7) << 5);
        short8 af = *(const short8*)(Cs + off);
        racc1 = __builtin_amdgcn_mfma_f32_16x16x32_bf16(af, bfr, racc1, 0, 0, 0);
      }
    }
    int j = l & 15;
    if (j < KRED) {
      #pragma unroll
      for (int r = 0; r < 4; ++r) {
        int row0 = (w << 5) + ((l >> 4) << 2) + r;
        redOut[((size_t)nt * BS + r0 + row0) * KRED + j] = racc0[r];
        redOut[((size_t)nt * BS + r0 + row0 + 16) * KRED + j] = racc1[r];
      }
    }
  }
}

// ---------------- layer-1 forward: out = tanh(x6 @ W1 + b1), bf16
__global__ __launch_bounds__(256) void l1fwd(const float* __restrict__ x,
                                             const float* __restrict__ W1,
                                             const float* __restrict__ b1,
                                             unsigned short* __restrict__ out) {
  int idx = blockIdx.x * 256 + threadIdx.x;
  int r = idx >> 7;
  int n8 = (idx & 127) << 3;
  const float* xr = x + (size_t)r * 10;
  float xs[6];
  #pragma unroll
  for (int k = 0; k < 6; ++k) xs[k] = xr[k];
  float4 bb0 = *(const float4*)(b1 + n8), bb1 = *(const float4*)(b1 + n8 + 4);
  float z[8] = {bb0.x, bb0.y, bb0.z, bb0.w, bb1.x, bb1.y, bb1.z, bb1.w};
  #pragma unroll
  for (int k = 0; k < 6; ++k) {
    const float* wrow = W1 + (size_t)k * HID + n8;
    float4 wa = *(const float4*)wrow, wb = *(const float4*)(wrow + 4);
    z[0] += xs[k] * wa.x; z[1] += xs[k] * wa.y; z[2] += xs[k] * wa.z; z[3] += xs[k] * wa.w;
    z[4] += xs[k] * wb.x; z[5] += xs[k] * wb.y; z[6] += xs[k] * wb.z; z[7] += xs[k] * wb.w;
  }
  ushort8v o;
  #pragma unroll
  for (int j = 0; j < 8; ++j) o[j] = f2bf(tanh_fast(z[j]));
  *(ushort8v*)(out + (size_t)r * HID + n8) = o;
}

// ---------------- JVP layer-1: th1 = (tang @ W1) * (1 - tanh(x@W1+b1)^2)
__global__ __launch_bounds__(256) void l1t(const float* __restrict__ x,
                                           const float* __restrict__ outbuf, // tangent in cols 0..5
                                           const float* __restrict__ W1,
                                           const float* __restrict__ b1,
                                           unsigned short* __restrict__ P) {
  int idx = blockIdx.x * 256 + threadIdx.x;
  int r = idx >> 7;
  int n8 = (idx & 127) << 3;
  const float* xr = x + (size_t)r * 10;
  const float* tr = outbuf + (size_t)r * 10;
  float xs[6], ts[6];
  #pragma unroll
  for (int k = 0; k < 6; ++k) { xs[k] = xr[k]; ts[k] = tr[k]; }
  float4 bb0 = *(const float4*)(b1 + n8), bb1 = *(const float4*)(b1 + n8 + 4);
  float z[8] = {bb0.x, bb0.y, bb0.z, bb0.w, bb1.x, bb1.y, bb1.z, bb1.w};
  float tz[8] = {};
  #pragma unroll
  for (int k = 0; k < 6; ++k) {
    const float* wrow = W1 + (size_t)k * HID + n8;
    float4 wa = *(const float4*)wrow, wb = *(const float4*)(wrow + 4);
    z[0] += xs[k] * wa.x;  z[1] += xs[k] * wa.y;  z[2] += xs[k] * wa.z;  z[3] += xs[k] * wa.w;
    z[4] += xs[k] * wb.x;  z[5] += xs[k] * wb.y;  z[6] += xs[k] * wb.z;  z[7] += xs[k] * wb.w;
    tz[0] += ts[k] * wa.x; tz[1] += ts[k] * wa.y; tz[2] += ts[k] * wa.z; tz[3] += ts[k] * wa.w;
    tz[4] += ts[k] * wb.x; tz[5] += ts[k] * wb.y; tz[6] += ts[k] * wb.z; tz[7] += ts[k] * wb.w;
  }
  ushort8v o;
  #pragma unroll
  for (int j = 0; j < 8; ++j) {
    float th = tanh_fast(z[j]);
    o[j] = f2bf(tz[j] * (1.f - th * th));
  }
  *(ushort8v*)(P + (size_t)r * HID + n8) = o;
}

// ---------------- g2 = (gL @ MW3^T) * (1-h2^2), bf16  (K = 9, h2 = tanh act)
__global__ __launch_bounds__(256) void k9bwd(const float* __restrict__ sGL,
                                             const float* __restrict__ MW3, // [1024][9]
                                             const unsigned short* __restrict__ h2,
                                             unsigned short* __restrict__ outp) {
  __shared__ float wsm[9216];
  int t = threadIdx.x;
  #pragma unroll
  for (int i = 0; i < 36; ++i) wsm[i * 256 + t] = MW3[i * 256 + t];
  __syncthreads();
  int idx = blockIdx.x * 256 + t;
  int r  = idx >> 7;
  int lc = idx & 127;
  const float* g = sGL + (size_t)r * 9;
  float gl[9];
  #pragma unroll
  for (int j = 0; j < 9; ++j) gl[j] = g[j];
  #pragma unroll
  for (int c = 0; c < 8; ++c) {
    int col = lc + (c << 7);
    const float* wr = wsm + col * 9;
    float s = 0.f;
    #pragma unroll
    for (int jj = 0; jj < 9; ++jj) s += gl[jj] * wr[jj];
    float h = bf2f(h2[(size_t)r * HID + col]);
    outp[(size_t)r * HID + col] = f2bf(s * (1.f - h * h));
  }
}

// ---------------- skinny reductions (fallback path only)
template<bool BIAS>
__global__ __launch_bounds__(256) void skinny9(const unsigned short* __restrict__ A,
                                               const float* __restrict__ W,  // [1024][9]
                                               const float* __restrict__ bias,
                                               float* __restrict__ out) {
  __shared__ float wsm[9216];
  {
    int t = threadIdx.x;
    #pragma unroll
    for (int i = 0; i < 36; ++i) wsm[i * 256 + t] = W[i * 256 + t];
  }
  __syncthreads();
  int wid = blockIdx.x * 4 + (threadIdx.x >> 6);
  int l = threadIdx.x & 63;
  const unsigned short* ar = A + (size_t)wid * HID;
  float acc[9] = {};
  for (int i = 0; i < 16; ++i) {
    int k = i * 64 + l;
    float a = bf2f(ar[k]);
    const float* wr = wsm + k * 9;
    #pragma unroll
    for (int j = 0; j < 9; ++j) acc[j] += a * wr[j];
  }
  #pragma unroll
  for (int j = 0; j < 9; ++j) {
    float sv = acc[j];
    for (int d = 32; d; d >>= 1) sv += __shfl_down(sv, d);
    if (l == 0) out[(size_t)wid * 9 + j] = BIAS ? (sv + bias[j]) : sv;
  }
}
__global__ __launch_bounds__(256) void skinny6(const unsigned short* __restrict__ A,
                                               const float* __restrict__ W,  // [6][1024]
                                               float* __restrict__ out) {
  int wid = blockIdx.x * 4 + (threadIdx.x >> 6);
  int l = threadIdx.x & 63;
  const unsigned short* ar = A + (size_t)wid * HID;
  float acc[6] = {};
  for (int i = 0; i < 4; ++i) {
    int k = i * 256 + l * 4;
    ushort4v av = *(const ushort4v*)(ar + k);
    float a0 = bf2f(av[0]), a1 = bf2f(av[1]), a2 = bf2f(av[2]), a3 = bf2f(av[3]);
    #pragma unroll
    for (int j = 0; j < 6; ++j) {
      float4 wv = *(const float4*)(W + (size_t)j * HID + k);
      acc[j] += a0 * wv.x + a1 * wv.y + a2 * wv.z + a3 * wv.w;
    }
  }
  #pragma unroll
  for (int j = 0; j < 6; ++j) {
    float sv = acc[j];
    for (int d = 32; d; d >>= 1) sv += __shfl_down(sv, d);
    if (l == 0) out[(size_t)wid * 6 + j] = sv;
  }
}
__global__ __launch_bounds__(256) void skinny3(const unsigned short* __restrict__ A,
                                               const float* __restrict__ W,  // [1024][3]
                                               const float* __restrict__ bias,
                                               float* __restrict__ out) {
  __shared__ float wsm[3072];
  {
    int t = threadIdx.x;
    #pragma unroll
    for (int i = 0; i < 12; ++i) wsm[i * 256 + t] = W[i * 256 + t];
  }
  __syncthreads();
  int wid = blockIdx.x * 4 + (threadIdx.x >> 6);
  int l = threadIdx.x & 63;
  const unsigned short* ar = A + (size_t)wid * HID;
  float a0 = 0.f, a1 = 0.f, a2 = 0.f;
  for (int i = 0; i < 16; ++i) {
    int k = i * 64 + l;
    float a = bf2f(ar[k]);
    const float* wr = wsm + k * 3;
    a0 += a * wr[0]; a1 += a * wr[1]; a2 += a * wr[2];
  }
  float acc[3] = {a0, a1, a2};
  #pragma unroll
  for (int j = 0; j < 3; ++j) {
    float sv = acc[j];
    for (int d = 32; d; d >>= 1) sv += __shfl_down(sv, d);
    if (l == 0) out[(size_t)wid * 3 + j] = sv + bias[j];
  }
}

// ---------------- per-row 3x3 algebra
__global__ __launch_bounds__(256) void rowA(const float* __restrict__ x,
                                            const float* __restrict__ sLvec,
                                            float* __restrict__ sP,
                                            float* __restrict__ sGL) {
  int r = blockIdx.x * 256 + threadIdx.x;
  const float* Lv = sLvec + (size_t)r * 9;
  float L[3][3];
  #pragma unroll
  for (int i = 0; i < 3; ++i)
    #pragma unroll
    for (int j = 0; j < 3; ++j) L[i][j] = Lv[3 * i + j];
  float a = 0.1f, b = 0.f, c = 0.f, d = 0.1f, e = 0.f, f = 0.1f;
  #pragma unroll
  for (int k = 0; k < 3; ++k) {
    a += L[0][k] * L[0][k]; b += L[0][k] * L[1][k]; c += L[0][k] * L[2][k];
    d += L[1][k] * L[1][k]; e += L[1][k] * L[2][k]; f += L[2][k] * L[2][k];
  }
  const float* xr = x + (size_t)r * 10;
  float q0 = xr[6], q1 = xr[7], q2 = xr[8];
  float c00 = d * f - e * e;
  float c01 = c * e - b * f;
  float c02 = b * e - c * d;
  float det = a * c00 + b * c01 + c * c02;
  float inv = 1.f / det;
  float i00 = c00 * inv, i01 = c01 * inv, i02 = c02 * inv;
  float i11 = (a * f - c * c) * inv;
  float i12 = (b * c - a * e) * inv;
  float i22 = (a * d - b * b) * inv;
  float p0 = i00 * q0 + i01 * q1 + i02 * q2;
  float p1 = i01 * q0 + i11 * q1 + i12 * q2;
  float p2 = i02 * q0 + i12 * q1 + i22 * q2;
  sP[(size_t)r * 3 + 0] = p0; sP[(size_t)r * 3 + 1] = p1; sP[(size_t)r * 3 + 2] = p2;
  float lt0 = p0 * L[0][0] + p1 * L[1][0] + p2 * L[2][0];
  float lt1 = p0 * L[0][1] + p1 * L[1][1] + p2 * L[2][1];
  float lt2 = p0 * L[0][2] + p1 * L[1][2] + p2 * L[2][2];
  float pp[3] = {p0, p1, p2}, lt[3] = {lt0, lt1, lt2};
  #pragma unroll
  for (int i = 0; i < 3; ++i)
    #pragma unroll
    for (int j = 0; j < 3; ++j) sGL[(size_t)r * 9 + 3 * i + j] = pp[i] * lt[j];
}

__global__ __launch_bounds__(256) void rowB(const float* __restrict__ x,
                                            const float* __restrict__ sGzM,
                                            const float* __restrict__ sGzV,
                                            const float* __restrict__ sGq,
                                            float* __restrict__ out,
                                            float* __restrict__ sDp) {
  int r = blockIdx.x * 256 + threadIdx.x;
  const float* xr = x + (size_t)r * 10;
  float u = xr[9];
  #pragma unroll
  for (int i = 0; i < 3; ++i) {
    float cosq = xr[i], sinq = xr[3 + i], qd = xr[6 + i];
    float dhc = sGzM[(size_t)r * 6 + i] + sGzV[(size_t)r * 6 + i];
    float dhs = sGzM[(size_t)r * 6 + 3 + i] + sGzV[(size_t)r * 6 + 3 + i];
    float F = sGq[(size_t)r * 3 + i] * u;
    float dq = qd;  // dHdp = M_inv @ p = q_dot exactly
    float dp = sinq * dhc - cosq * dhs + F;
    out[(size_t)r * 10 + i]     = -sinq * dq;
    out[(size_t)r * 10 + 3 + i] =  cosq * dq;
    sDp[(size_t)r * 3 + i] = dp;
  }
}

__global__ __launch_bounds__(256) void rowC(const float* __restrict__ sLvec,
                                            const float* __restrict__ sTL,
                                            const float* __restrict__ sP,
                                            const float* __restrict__ sDp,
                                            float* __restrict__ out) {
  int r = blockIdx.x * 256 + threadIdx.x;
  float L[3][3], T[3][3];
  #pragma unroll
  for (int i = 0; i < 3; ++i)
    #pragma unroll
    for (int j = 0; j < 3; ++j) {
      L[i][j] = sLvec[(size_t)r * 9 + 3 * i + j];
      T[i][j] = sTL[(size_t)r * 9 + 3 * i + j];
    }
  float Mi[3][3], dM[3][3];
  #pragma unroll
  for (int i = 0; i < 3; ++i) {
    #pragma unroll
    for (int j = 0; j < 3; ++j) {
      float s = 0.f, sd = 0.f;
      #pragma unroll
      for (int k = 0; k < 3; ++k) {
        s  += L[i][k] * L[j][k];
        sd += T[i][k] * L[j][k] + L[i][k] * T[j][k];
      }
      Mi[i][j] = s + (i == j ? 0.1f : 0.f);
      dM[i][j] = sd;
    }
  }
  float p[3], dp[3];
  #pragma unroll
  for (int i = 0; i < 3; ++i) { p[i] = sP[(size_t)r * 3 + i]; dp[i] = sDp[(size_t)r * 3 + i]; }
  #pragma unroll
  for (int i = 0; i < 3; ++i) {
    float s = 0.f;
    #pragma unroll
    for (int j = 0; j < 3; ++j) s += Mi[i][j] * dp[j] + dM[i][j] * p[j];
    out[(size_t)r * 10 + 6 + i] = s;
  }
  out[(size_t)r * 10 + 9] = 0.f;
}

// ---------------- host
extern "C" void kernel_launch(void* const* d_in, const int* in_sizes, int n_in,
                              void* d_out, int out_size, void* d_ws, size_t ws_size,
                              hipStream_t stream) {
  const float* x   = (const float*)d_in[1];
  const float* MW1 = (const float*)d_in[2];
  const float* Mb1 = (const float*)d_in[3];
  const float* MW2 = (const float*)d_in[4];
  const float* Mb2 = (const float*)d_in[5];
  const float* MW3 = (const float*)d_in[6];
  const float* Mb3 = (const float*)d_in[7];
  const float* VW1 = (const float*)d_in[8];
  const float* Vb1 = (const float*)d_in[9];
  const float* VW2 = (const float*)d_in[10];
  const float* Vb2 = (const float*)d_in[11];
  const float* VW3 = (const float*)d_in[12];
  const float* GW1 = (const float*)d_in[14];
  const float* Gb1 = (const float*)d_in[15];
  const float* GW2 = (const float*)d_in[16];
  const float* Gb2 = (const float*)d_in[17];
  const float* GW3 = (const float*)d_in[18];
  const float* Gb3 = (const float*)d_in[19];
  float* out = (float*)d_out;
  char* ws = (char*)d_ws;

  const size_t PK   = (size_t)HID * HID * 2;
  const size_t BUF  = (size_t)BS * HID * 2;
  const size_t SCAL = (size_t)BS * 48 * 4;
  const size_t NEED = 5 * PK + 3 * BUF + SCAL;
  const size_t PART = (size_t)8 * BS * 9 * 4;        // 9.44 MB partials
  if (ws_size < NEED) return;  // ws too small: fail visibly (output untouched)
  const bool FUSED = (ws_size >= NEED + PART);

  unsigned short* MW2p  = (unsigned short*)(ws + 0 * PK);
  unsigned short* MW2tp = (unsigned short*)(ws + 1 * PK);
  unsigned short* VW2p  = (unsigned short*)(ws + 2 * PK);
  unsigned short* VW2tp = (unsigned short*)(ws + 3 * PK);
  unsigned short* GW2p  = (unsigned short*)(ws + 4 * PK);
  unsigned short* P = (unsigned short*)(ws + 5 * PK);
  unsigned short* Q = (unsigned short*)(ws + 5 * PK + BUF);
  unsigned short* R = (unsigned short*)(ws + 5 * PK + 2 * BUF);
  char* s = ws + 5 * PK + 3 * BUF;
  float* sLvec = (float*)(s);
  float* sP    = (float*)(s + (size_t)BS *  9 * 4);
  float* sGL   = (float*)(s + (size_t)BS * 12 * 4);
  float* sGzM  = (float*)(s + (size_t)BS * 21 * 4);
  float* sGzV  = (float*)(s + (size_t)BS * 27 * 4);
  float* sGq   = (float*)(s + (size_t)BS * 33 * 4);
  float* sDp   = (float*)(s + (size_t)BS * 36 * 4);
  float* sTL   = (float*)(s + (size_t)BS * 39 * 4);
  float* Pp    = (float*)(s + SCAL);                  // partials (fused path)

  dim3 B(256);
  const int G_GEMM = 2048;          // 256 mt x 8 nt
  const int G_EW   = BS * 128 / 256; // 16384
  const int G_SK   = BS / 4;         // 8192
  const int G_ROW  = BS / 256;       // 128

  // weight packing
  pack_w<<<256, B, 0, stream>>>(MW2, MW2p, MW2tp);
  pack_w<<<256, B, 0, stream>>>(VW2, VW2p, VW2tp);
  pack_w<<<256, B, 0, stream>>>(GW2, GW2p, nullptr);

  if (FUSED) {
    // M forward: h2 -> Q (kept), fused red9(MW3) -> partials -> sLvec (+Mb3)
    l1fwd<<<G_EW, B, 0, stream>>>(x, MW1, Mb1, P);                                // h1M
    gemm_bf16<0, 9, false><<<G_GEMM, B, 0, stream>>>(P, MW2p, Q, Mb2, nullptr, nullptr, MW3, Pp);
    sumP<9><<<BS * 9 / 256, B, 0, stream>>>(Pp, Mb3, sLvec);
    rowA<<<G_ROW, B, 0, stream>>>(x, sLvec, sP, sGL);                             // p, gL

    // M backward: g2 -> R; g1 fused red6(MW1) -> sGzM (C skipped; aux=P)
    k9bwd<<<G_EW, B, 0, stream>>>(sGL, MW3, Q, R);                                // g2
    gemm_bf16<1, 6, true><<<G_GEMM, B, 0, stream>>>(R, MW2tp, P, nullptr, P, nullptr, MW1, Pp);
    sumP<6><<<BS * 6 / 256, B, 0, stream>>>(Pp, nullptr, sGzM);

    // G forward: h2G fused red3(GW3) -> sGq (+Gb3), C skipped
    l1fwd<<<G_EW, B, 0, stream>>>(x, GW1, Gb1, P);
    gemm_bf16<0, 3, true><<<G_GEMM, B, 0, stream>>>(P, GW2p, R, Gb2, nullptr, nullptr, GW3, Pp);
    sumP<3><<<BS * 3 / 256, B, 0, stream>>>(Pp, Gb3, sGq);

    // V backward: gv2 -> R (fused mapV); gv1 fused red6(VW1) -> sGzV, C skipped
    l1fwd<<<G_EW, B, 0, stream>>>(x, VW1, Vb1, P);                                // vh1
    gemm_bf16<2, 0, false><<<G_GEMM, B, 0, stream>>>(P, VW2p, R, Vb2, nullptr, VW3, nullptr, nullptr);
    gemm_bf16<1, 6, true><<<G_GEMM, B, 0, stream>>>(R, VW2tp, P, nullptr, P, nullptr, VW1, Pp);
    sumP<6><<<BS * 6 / 256, B, 0, stream>>>(Pp, nullptr, sGzV);

    // assemble tangent, dp; write out[:, 0:6]
    rowB<<<G_ROW, B, 0, stream>>>(x, sGzM, sGzV, sGq, out, sDp);

    // JVP: th2 fused red9(MW3) -> sTL, C skipped (aux = h2 in Q)
    l1t<<<G_EW, B, 0, stream>>>(x, out, MW1, Mb1, P);                             // th1
    gemm_bf16<1, 9, true><<<G_GEMM, B, 0, stream>>>(P, MW2p, R, nullptr, Q, nullptr, MW3, Pp);
    sumP<9><<<BS * 9 / 256, B, 0, stream>>>(Pp, nullptr, sTL);

    rowC<<<G_ROW, B, 0, stream>>>(sLvec, sTL, sP, sDp, out);
  } else {
    // fallback: verified R19 sequence
    l1fwd<<<G_EW, B, 0, stream>>>(x, MW1, Mb1, P);                                // h1M
    gemm_bf16<0, 0, false><<<G_GEMM, B, 0, stream>>>(P, MW2p, Q, Mb2, nullptr, nullptr, nullptr, nullptr);
    skinny9<true><<<G_SK, B, 0, stream>>>(Q, MW3, Mb3, sLvec);
    rowA<<<G_ROW, B, 0, stream>>>(x, sLvec, sP, sGL);

    k9bwd<<<G_EW, B, 0, stream>>>(sGL, MW3, Q, R);                                // g2
    gemm_bf16<1, 0, false><<<G_GEMM, B, 0, stream>>>(R, MW2tp, P, nullptr, P, nullptr, nullptr, nullptr);
    skinny6<<<G_SK, B, 0, stream>>>(P, MW1, sGzM);

    l1fwd<<<G_EW, B, 0, stream>>>(x, GW1, Gb1, P);
    gemm_bf16<0, 0, false><<<G_GEMM, B, 0, stream>>>(P, GW2p, R, Gb2, nullptr, nullptr, nullptr, nullptr);
    skinny3<<<G_SK, B, 0, stream>>>(R, GW3, Gb3, sGq);

    l1fwd<<<G_EW, B, 0, stream>>>(x, VW1, Vb1, P);                                // vh1
    gemm_bf16<2, 0, false><<<G_GEMM, B, 0, stream>>>(P, VW2p, R, Vb2, nullptr, VW3, nullptr, nullptr);
    gemm_bf16<1, 0, false><<<G_GEMM, B, 0, stream>>>(R, VW2tp, P, nullptr, P, nullptr, nullptr, nullptr);
    skinny6<<<G_SK, B, 0, stream>>>(P, VW1, sGzV);

    rowB<<<G_ROW, B, 0, stream>>>(x, sGzM, sGzV, sGq, out, sDp);

    l1t<<<G_EW, B, 0, stream>>>(x, out, MW1, Mb1, P);                             // th1
    gemm_bf16<1, 0, false><<<G_GEMM, B, 0, stream>>>(P, MW2p, R, nullptr, Q, nullptr, nullptr, nullptr);
    skinny9<false><<<G_SK, B, 0, stream>>>(R, MW3, nullptr, sTL);

    rowC<<<G_ROW, B, 0, stream>>>(sLvec, sTL, sP, sDp, out);
  }
}

// Round 24
// 708.622 us; speedup vs baseline: 1.0054x; 1.0054x over previous
//
#include <hip/hip_runtime.h>

// HNN structure embed (N=3, HID=1024, bs=32768).
// GEMMs: bf16 MFMA 16x16x32, 128x128x64 tiles, 2-slot LDS ring (64 KB),
// minimal 2-phase loop, __launch_bounds__(256,2), in-place EPI1 aliasing,
// MFMA-based fused skinny reductions with race-free partials.
// R24: the two red9 sumP collapses absorbed into their consumers (rowA sums
// M-fwd partials + Mb3 and writes sLvec; rowC sums the JVP partials
// directly, sTL eliminated). The 6/3-wide collapses keep sumP (their Pp
// region is overwritten before their consumers run). -2 launches.
// Per-row 3x3 algebra in f32. dHdp == q_dot (exact). V layer-3 fwd skipped.

#define HID 1024
#define BS  32768

typedef __attribute__((ext_vector_type(8))) short short8;
typedef __attribute__((ext_vector_type(4))) float f32x4;
typedef __attribute__((ext_vector_type(8))) unsigned short ushort8v;
typedef __attribute__((ext_vector_type(4))) unsigned short ushort4v;

typedef __attribute__((address_space(1))) const char gconst_char;
typedef __attribute__((address_space(3))) char lds_char;

__device__ __forceinline__ unsigned short f2bf(float f) {
  unsigned int u = __builtin_bit_cast(unsigned int, f);
  u += 0x7fffu + ((u >> 16) & 1u);   // RNE
  return (unsigned short)(u >> 16);
}
__device__ __forceinline__ float bf2f(unsigned short s) {
  unsigned int u = ((unsigned int)s) << 16;
  return __builtin_bit_cast(float, u);
}
__device__ __forceinline__ float tanh_fast(float x) {
  float e = __builtin_amdgcn_exp2f(x * 2.885390081777927f); // e^(2x)
  return 1.f - 2.f * __builtin_amdgcn_rcpf(e + 1.f);
}

// ---------------- weight packing: pT[n][k]=bf16(W[k][n]); pC[n][k]=bf16(W[n][k])
__global__ __launch_bounds__(256) void pack_w(const float* __restrict__ W,
                                              unsigned short* __restrict__ pT,
                                              unsigned short* __restrict__ pC) {
  __shared__ float tile[64][65];
  int b = blockIdx.x;
  int k0 = (b >> 4) << 6;
  int n0 = (b & 15) << 6;
  int t = threadIdx.x;
  for (int i = 0; i < 16; ++i) {
    int idx = i * 256 + t;
    int r = idx >> 6, c = idx & 63;
    tile[r][c] = W[(size_t)(k0 + r) * HID + n0 + c];
  }
  if (pC) {
    for (int i = 0; i < 16; ++i) {
      int idx = i * 256 + t;
      int r = idx >> 6, c = idx & 63;
      pC[(size_t)(n0 + r) * HID + k0 + c] = f2bf(W[(size_t)(n0 + r) * HID + k0 + c]);
    }
  }
  __syncthreads();
  for (int i = 0; i < 16; ++i) {
    int idx = i * 256 + t;
    int n = idx >> 6, k = idx & 63;
    pT[(size_t)(n0 + n) * HID + k0 + k] = f2bf(tile[k][n]);
  }
}

// ---------------- partial-sum collapse: out[idx] = sum_nt Pp[nt][idx] (+bias)
template<int KR>
__global__ __launch_bounds__(256) void sumP(const float* __restrict__ Pp,
                                            const float* __restrict__ bias,
                                            float* __restrict__ outv) {
  int idx = blockIdx.x * 256 + threadIdx.x;   // over BS*KR
  float sv = 0.f;
  #pragma unroll
  for (int nt = 0; nt < 8; ++nt) sv += Pp[(size_t)nt * BS * KR + idx];
  if (bias) {
    int j = idx - (idx / KR) * KR;
    sv += bias[j];
  }
  outv[idx] = sv;
}

// ---------------- big GEMM: C[m][n] = epi( sum_k A[m][k]*Bp[n][k] )
// EPI 0: tanh(acc + bias[col])
// EPI 1: acc * (1 - bf2f(aux[row][col])^2)  (aux = bf16 tanh act; may alias C)
// EPI 2: w3[col] * (1 - tanh(acc + bias[col])^2)   (fused mapV)
// KRED>0: fused reduction red[row][j] = sum_col epi_val[row][col]*W[col][j],
//   computed via MFMA from the LDS C tile; partials stored race-free to
//   redOut[(nt*BS + r0+row)*KRED + j].
//   KRED==6: redW layout [6][1024];  KRED==3/9: redW layout [1024][KRED].
// SKIPC: skip global C store (output consumed only by the reduction).
template<int EPI, int KRED, bool SKIPC>
__global__ __launch_bounds__(256, 2) void gemm_bf16(
    const unsigned short* __restrict__ A,
    const unsigned short* __restrict__ Bp,
    unsigned short* __restrict__ C,
    const float* __restrict__ bias,
    const unsigned short* __restrict__ aux,
    const float* __restrict__ w3,
    const float* __restrict__ redW,
    float* __restrict__ redOut)
{
  __shared__ __align__(1024) char lds[65536];   // 2 x (A 16K + B 16K)
  const int t = threadIdx.x;
  const int w = t >> 6, l = t & 63;
  // bijective XCD swizzle: 2048 blocks, 8 XCDs -> each XCD owns 32 M-panels
  int bid = (int)blockIdx.x;
  int wg  = (bid & 7) * 256 + (bid >> 3);
  const int nt = wg & 7, mt = wg >> 3;
  const int r0 = mt << 7, n0 = nt << 7;
  const int wr = w >> 1, wc = w & 1;

  f32x4 acc[4][4] = {};
  const int lbase = (w << 2);

  const char* Abase = (const char*)A  + ((size_t)r0 << 11);
  const char* Bbase = (const char*)Bp + ((size_t)n0 << 11);

  auto STAGE = [&](char* Ad, int kt) {
    char* Bd = Ad + 16384;
    const char* Ak = Abase + kt * 128;
    const char* Bk = Bbase + kt * 128;
    #pragma unroll
    for (int i = 0; i < 4; ++i) {
      int o   = ((lbase + i) << 10) + (l << 4);
      int row = o >> 7;
      int vo  = (row << 11) + ((o & 127) ^ ((row & 7) << 4));   // inv swizzle on SOURCE
      __builtin_amdgcn_global_load_lds((gconst_char*)(Ak + vo), (lds_char*)(Ad + ((lbase + i) << 10)), 16, 0, 0);
      __builtin_amdgcn_global_load_lds((gconst_char*)(Bk + vo), (lds_char*)(Bd + ((lbase + i) << 10)), 16, 0, 0);
    }
  };

  auto COMPUTE = [&](const char* As) {
    const char* Bs = As + 16384;
    #pragma unroll
    for (int kk = 0; kk < 2; ++kk) {
      short8 bfr[4];
      #pragma unroll
      for (int n = 0; n < 4; ++n) {
        int col = (wc << 6) + (n << 4) + (l & 15);
        int off = (col << 7) + ((l >> 4) << 4) + (kk << 6);
        off ^= ((col & 7) << 4);
        bfr[n] = *(const short8*)(Bs + off);
      }
      #pragma unroll
      for (int m = 0; m < 4; ++m) {
        int row = (wr << 6) + (m << 4) + (l & 15);
        int off = (row << 7) + ((l >> 4) << 4) + (kk << 6);
        off ^= ((row & 7) << 4);
        short8 af = *(const short8*)(As + off);
        #pragma unroll
        for (int n = 0; n < 4; ++n) {
          acc[m][n] = __builtin_amdgcn_mfma_f32_16x16x32_bf16(af, bfr[n], acc[m][n], 0, 0, 0);
        }
      }
    }
  };

  char* L0 = lds;
  char* L1 = lds + 32768;

  // prologue: tile 0 into L0, drain, sync
  STAGE(L0, 0);
  asm volatile("s_waitcnt vmcnt(0)" ::: "memory");
  __builtin_amdgcn_s_barrier();

  // minimal 2-phase: STAGE(next) -> COMPUTE(cur) -> vmcnt(0) -> barrier.
  #pragma unroll 1
  for (int kt2 = 0; kt2 < 7; ++kt2) {
    STAGE(L1, 2 * kt2 + 1);
    COMPUTE(L0);
    asm volatile("s_waitcnt vmcnt(0)" ::: "memory");
    __builtin_amdgcn_s_barrier();
    STAGE(L0, 2 * kt2 + 2);
    COMPUTE(L1);
    asm volatile("s_waitcnt vmcnt(0)" ::: "memory");
    __builtin_amdgcn_s_barrier();
  }
  STAGE(L1, 15);
  COMPUTE(L0);
  asm volatile("s_waitcnt vmcnt(0)" ::: "memory");
  __builtin_amdgcn_s_barrier();
  COMPUTE(L1);
  __syncthreads();   // ds_reads retired before epilogue reuses LDS

  // stage reduction weights as bf16 wjk[j=0..15][col=0..127], 272B rows
  // (j >= KRED rows zeroed). B-frag reads are 16B contiguous per lane.
  char* wjk = lds + 32768;
  if (KRED == 9) {
    int col = t >> 1;
    if ((t & 1) == 0) {
      #pragma unroll
      for (int j = 0; j < 8; ++j) {
        float v = redW[(size_t)(n0 + col) * 9 + j];
        *(unsigned short*)(wjk + j * 272 + col * 2) = f2bf(v);
      }
    } else {
      #pragma unroll
      for (int j = 8; j < 16; ++j) {
        float v = (j == 8) ? redW[(size_t)(n0 + col) * 9 + 8] : 0.f;
        *(unsigned short*)(wjk + j * 272 + col * 2) = f2bf(v);
      }
    }
  } else if (KRED == 3) {
    int col = t >> 1;
    if ((t & 1) == 0) {
      #pragma unroll
      for (int j = 0; j < 8; ++j) {
        float v = (j < 3) ? redW[(size_t)(n0 + col) * 3 + j] : 0.f;
        *(unsigned short*)(wjk + j * 272 + col * 2) = f2bf(v);
      }
    } else {
      #pragma unroll
      for (int j = 8; j < 16; ++j) {
        *(unsigned short*)(wjk + j * 272 + col * 2) = 0;
      }
    }
  } else if (KRED == 6) {
    int col = t & 127;
    #pragma unroll
    for (int it = 0; it < 8; ++it) {
      int j = it * 2 + (t >> 7);
      float v = (j < 6) ? redW[(size_t)j * HID + n0 + col] : 0.f;
      *(unsigned short*)(wjk + j * 272 + col * 2) = f2bf(v);
    }
  }

  // epilogue: apply epi, stage bf16 tile in LDS (swizzled)
  char* Cs = lds;
  #pragma unroll
  for (int n = 0; n < 4; ++n) {
    const int colL = (wc << 6) + (n << 4) + (l & 15);
    const int gcol = n0 + colL;
    float bval = 0.f, w3v = 0.f;
    if (EPI == 0 || EPI == 2) bval = bias[gcol];
    if (EPI == 2) w3v = w3[gcol];
    #pragma unroll
    for (int m = 0; m < 4; ++m) {
      #pragma unroll
      for (int r = 0; r < 4; ++r) {
        const int rowL = (wr << 6) + (m << 4) + ((l >> 4) << 2) + r;
        float v = acc[m][n][r];
        if (EPI == 0) {
          v = tanh_fast(v + bval);
        } else if (EPI == 1) {
          float h = bf2f(aux[((size_t)(r0 + rowL) << 10) + gcol]);
          v *= (1.f - h * h);
        } else {
          float th = tanh_fast(v + bval);
          v = w3v * (1.f - th * th);
        }
        int so = (rowL << 8) + (colL << 1);
        so ^= ((rowL & 7) << 5);
        *(unsigned short*)(Cs + so) = f2bf(v);
      }
      __builtin_amdgcn_sched_barrier(0);   // cap live acc reads per chunk
    }
  }
  __syncthreads();   // all aux reads + Cs/wjk writes done

  // optional global C store (coalesced from swizzled LDS tile)
  if (!SKIPC) {
    #pragma unroll
    for (int j = 0; j < 8; ++j) {
      int o    = (j << 12) + (t << 4);
      int rowL = o >> 8;
      int ir   = o & 255;
      uint4 v = *(const uint4*)(Cs + ((rowL << 8) + (ir ^ ((rowL & 7) << 5))));
      *(uint4*)(C + ((size_t)(r0 + rowL) << 10) + n0 + (ir >> 1)) = v;
      __builtin_amdgcn_sched_barrier(0);  // cap store live set
    }
  }

  // fused reduction via MFMA: red[row][j] = sum_col Cs[row][col]*wjk[j][col].
  // Wave w covers rows w*32..w*32+31 (2 m-frags), K=128 in 4 steps.
  if (KRED > 0) {
    f32x4 racc0 = {0.f, 0.f, 0.f, 0.f};
    f32x4 racc1 = {0.f, 0.f, 0.f, 0.f};
    #pragma unroll
    for (int kt = 0; kt < 4; ++kt) {
      short8 bfr = *(const short8*)(wjk + (l & 15) * 272 + (kt << 6) + ((l >> 4) << 4));
      {
        int row = (w << 5) + (l & 15);
        int off = (row << 8) + (kt << 6) + ((l >> 4) << 4);
        off ^= ((row & 7) << 5);
        short8 af = *(const short8*)(Cs + off);
        racc0 = __builtin_amdgcn_mfma_f32_16x16x32_bf16(af, bfr, racc0, 0, 0, 0);
      }
      {
        int row = (w << 5) + 16 + (l & 15);
        int off = (row << 8) + (kt << 6) + ((l >> 4) << 4);
        off ^= ((row & 7) << 5);
        short8 af = *(const short8*)(Cs + off);
        racc1 = __builtin_amdgcn_mfma_f32_16x16x32_bf16(af, bfr, racc1, 0, 0, 0);
      }
    }
    int j = l & 15;
    if (j < KRED) {
      #pragma unroll
      for (int r = 0; r < 4; ++r) {
        int row0 = (w << 5) + ((l >> 4) << 2) + r;
        redOut[((size_t)nt * BS + r0 + row0) * KRED + j] = racc0[r];
        redOut[((size_t)nt * BS + r0 + row0 + 16) * KRED + j] = racc1[r];
      }
    }
  }
}

// ---------------- layer-1 forward: out = tanh(x6 @ W1 + b1), bf16
__global__ __launch_bounds__(256) void l1fwd(const float* __restrict__ x,
                                             const float* __restrict__ W1,
                                             const float* __restrict__ b1,
                                             unsigned short* __restrict__ out) {
  int idx = blockIdx.x * 256 + threadIdx.x;
  int r = idx >> 7;
  int n8 = (idx & 127) << 3;
  const float* xr = x + (size_t)r * 10;
  float xs[6];
  #pragma unroll
  for (int k = 0; k < 6; ++k) xs[k] = xr[k];
  float4 bb0 = *(const float4*)(b1 + n8), bb1 = *(const float4*)(b1 + n8 + 4);
  float z[8] = {bb0.x, bb0.y, bb0.z, bb0.w, bb1.x, bb1.y, bb1.z, bb1.w};
  #pragma unroll
  for (int k = 0; k < 6; ++k) {
    const float* wrow = W1 + (size_t)k * HID + n8;
    float4 wa = *(const float4*)wrow, wb = *(const float4*)(wrow + 4);
    z[0] += xs[k] * wa.x; z[1] += xs[k] * wa.y; z[2] += xs[k] * wa.z; z[3] += xs[k] * wa.w;
    z[4] += xs[k] * wb.x; z[5] += xs[k] * wb.y; z[6] += xs[k] * wb.z; z[7] += xs[k] * wb.w;
  }
  ushort8v o;
  #pragma unroll
  for (int j = 0; j < 8; ++j) o[j] = f2bf(tanh_fast(z[j]));
  *(ushort8v*)(out + (size_t)r * HID + n8) = o;
}

// ---------------- JVP layer-1: th1 = (tang @ W1) * (1 - tanh(x@W1+b1)^2)
__global__ __launch_bounds__(256) void l1t(const float* __restrict__ x,
                                           const float* __restrict__ outbuf, // tangent in cols 0..5
                                           const float* __restrict__ W1,
                                           const float* __restrict__ b1,
                                           unsigned short* __restrict__ P) {
  int idx = blockIdx.x * 256 + threadIdx.x;
  int r = idx >> 7;
  int n8 = (idx & 127) << 3;
  const float* xr = x + (size_t)r * 10;
  const float* tr = outbuf + (size_t)r * 10;
  float xs[6], ts[6];
  #pragma unroll
  for (int k = 0; k < 6; ++k) { xs[k] = xr[k]; ts[k] = tr[k]; }
  float4 bb0 = *(const float4*)(b1 + n8), bb1 = *(const float4*)(b1 + n8 + 4);
  float z[8] = {bb0.x, bb0.y, bb0.z, bb0.w, bb1.x, bb1.y, bb1.z, bb1.w};
  float tz[8] = {};
  #pragma unroll
  for (int k = 0; k < 6; ++k) {
    const float* wrow = W1 + (size_t)k * HID + n8;
    float4 wa = *(const float4*)wrow, wb = *(const float4*)(wrow + 4);
    z[0] += xs[k] * wa.x;  z[1] += xs[k] * wa.y;  z[2] += xs[k] * wa.z;  z[3] += xs[k] * wa.w;
    z[4] += xs[k] * wb.x;  z[5] += xs[k] * wb.y;  z[6] += xs[k] * wb.z;  z[7] += xs[k] * wb.w;
    tz[0] += ts[k] * wa.x; tz[1] += ts[k] * wa.y; tz[2] += ts[k] * wa.z; tz[3] += ts[k] * wa.w;
    tz[4] += ts[k] * wb.x; tz[5] += ts[k] * wb.y; tz[6] += ts[k] * wb.z; tz[7] += ts[k] * wb.w;
  }
  ushort8v o;
  #pragma unroll
  for (int j = 0; j < 8; ++j) {
    float th = tanh_fast(z[j]);
    o[j] = f2bf(tz[j] * (1.f - th * th));
  }
  *(ushort8v*)(P + (size_t)r * HID + n8) = o;
}

// ---------------- g2 = (gL @ MW3^T) * (1-h2^2), bf16  (K = 9, h2 = tanh act)
__global__ __launch_bounds__(256) void k9bwd(const float* __restrict__ sGL,
                                             const float* __restrict__ MW3, // [1024][9]
                                             const unsigned short* __restrict__ h2,
                                             unsigned short* __restrict__ outp) {
  __shared__ float wsm[9216];
  int t = threadIdx.x;
  #pragma unroll
  for (int i = 0; i < 36; ++i) wsm[i * 256 + t] = MW3[i * 256 + t];
  __syncthreads();
  int idx = blockIdx.x * 256 + t;
  int r  = idx >> 7;
  int lc = idx & 127;
  const float* g = sGL + (size_t)r * 9;
  float gl[9];
  #pragma unroll
  for (int j = 0; j < 9; ++j) gl[j] = g[j];
  #pragma unroll
  for (int c = 0; c < 8; ++c) {
    int col = lc + (c << 7);
    const float* wr = wsm + col * 9;
    float s = 0.f;
    #pragma unroll
    for (int jj = 0; jj < 9; ++jj) s += gl[jj] * wr[jj];
    float h = bf2f(h2[(size_t)r * HID + col]);
    outp[(size_t)r * HID + col] = f2bf(s * (1.f - h * h));
  }
}

// ---------------- skinny reductions (fallback path only)
template<bool BIAS>
__global__ __launch_bounds__(256) void skinny9(const unsigned short* __restrict__ A,
                                               const float* __restrict__ W,  // [1024][9]
                                               const float* __restrict__ bias,
                                               float* __restrict__ out) {
  __shared__ float wsm[9216];
  {
    int t = threadIdx.x;
    #pragma unroll
    for (int i = 0; i < 36; ++i) wsm[i * 256 + t] = W[i * 256 + t];
  }
  __syncthreads();
  int wid = blockIdx.x * 4 + (threadIdx.x >> 6);
  int l = threadIdx.x & 63;
  const unsigned short* ar = A + (size_t)wid * HID;
  float acc[9] = {};
  for (int i = 0; i < 16; ++i) {
    int k = i * 64 + l;
    float a = bf2f(ar[k]);
    const float* wr = wsm + k * 9;
    #pragma unroll
    for (int j = 0; j < 9; ++j) acc[j] += a * wr[j];
  }
  #pragma unroll
  for (int j = 0; j < 9; ++j) {
    float sv = acc[j];
    for (int d = 32; d; d >>= 1) sv += __shfl_down(sv, d);
    if (l == 0) out[(size_t)wid * 9 + j] = BIAS ? (sv + bias[j]) : sv;
  }
}
__global__ __launch_bounds__(256) void skinny6(const unsigned short* __restrict__ A,
                                               const float* __restrict__ W,  // [6][1024]
                                               float* __restrict__ out) {
  int wid = blockIdx.x * 4 + (threadIdx.x >> 6);
  int l = threadIdx.x & 63;
  const unsigned short* ar = A + (size_t)wid * HID;
  float acc[6] = {};
  for (int i = 0; i < 4; ++i) {
    int k = i * 256 + l * 4;
    ushort4v av = *(const ushort4v*)(ar + k);
    float a0 = bf2f(av[0]), a1 = bf2f(av[1]), a2 = bf2f(av[2]), a3 = bf2f(av[3]);
    #pragma unroll
    for (int j = 0; j < 6; ++j) {
      float4 wv = *(const float4*)(W + (size_t)j * HID + k);
      acc[j] += a0 * wv.x + a1 * wv.y + a2 * wv.z + a3 * wv.w;
    }
  }
  #pragma unroll
  for (int j = 0; j < 6; ++j) {
    float sv = acc[j];
    for (int d = 32; d; d >>= 1) sv += __shfl_down(sv, d);
    if (l == 0) out[(size_t)wid * 6 + j] = sv;
  }
}
__global__ __launch_bounds__(256) void skinny3(const unsigned short* __restrict__ A,
                                               const float* __restrict__ W,  // [1024][3]
                                               const float* __restrict__ bias,
                                               float* __restrict__ out) {
  __shared__ float wsm[3072];
  {
    int t = threadIdx.x;
    #pragma unroll
    for (int i = 0; i < 12; ++i) wsm[i * 256 + t] = W[i * 256 + t];
  }
  __syncthreads();
  int wid = blockIdx.x * 4 + (threadIdx.x >> 6);
  int l = threadIdx.x & 63;
  const unsigned short* ar = A + (size_t)wid * HID;
  float a0 = 0.f, a1 = 0.f, a2 = 0.f;
  for (int i = 0; i < 16; ++i) {
    int k = i * 64 + l;
    float a = bf2f(ar[k]);
    const float* wr = wsm + k * 3;
    a0 += a * wr[0]; a1 += a * wr[1]; a2 += a * wr[2];
  }
  float acc[3] = {a0, a1, a2};
  #pragma unroll
  for (int j = 0; j < 3; ++j) {
    float sv = acc[j];
    for (int d = 32; d; d >>= 1) sv += __shfl_down(sv, d);
    if (l == 0) out[(size_t)wid * 3 + j] = sv + bias[j];
  }
}

// ---------------- per-row 3x3 algebra
// FROMPART: sLvec is computed here from the 8 per-block partials + Mb3 and
// written out (rowC still reads it); else read precomputed sLvec.
template<bool FROMPART>
__global__ __launch_bounds__(256) void rowA(const float* __restrict__ x,
                                            float* __restrict__ sLvec,
                                            const float* __restrict__ Pp,
                                            const float* __restrict__ Mb3,
                                            float* __restrict__ sP,
                                            float* __restrict__ sGL) {
  int r = blockIdx.x * 256 + threadIdx.x;
  float L[3][3];
  if (FROMPART) {
    float lv[9];
    #pragma unroll
    for (int j = 0; j < 9; ++j) lv[j] = Mb3[j];
    #pragma unroll
    for (int nt = 0; nt < 8; ++nt) {
      const float* pp = Pp + ((size_t)nt * BS + r) * 9;
      #pragma unroll
      for (int j = 0; j < 9; ++j) lv[j] += pp[j];
    }
    #pragma unroll
    for (int j = 0; j < 9; ++j) sLvec[(size_t)r * 9 + j] = lv[j];
    #pragma unroll
    for (int i = 0; i < 3; ++i)
      #pragma unroll
      for (int j = 0; j < 3; ++j) L[i][j] = lv[3 * i + j];
  } else {
    const float* Lv = sLvec + (size_t)r * 9;
    #pragma unroll
    for (int i = 0; i < 3; ++i)
      #pragma unroll
      for (int j = 0; j < 3; ++j) L[i][j] = Lv[3 * i + j];
  }
  float a = 0.1f, b = 0.f, c = 0.f, d = 0.1f, e = 0.f, f = 0.1f;
  #pragma unroll
  for (int k = 0; k < 3; ++k) {
    a += L[0][k] * L[0][k]; b += L[0][k] * L[1][k]; c += L[0][k] * L[2][k];
    d += L[1][k] * L[1][k]; e += L[1][k] * L[2][k]; f += L[2][k] * L[2][k];
  }
  const float* xr = x + (size_t)r * 10;
  float q0 = xr[6], q1 = xr[7], q2 = xr[8];
  float c00 = d * f - e * e;
  float c01 = c * e - b * f;
  float c02 = b * e - c * d;
  float det = a * c00 + b * c01 + c * c02;
  float inv = 1.f / det;
  float i00 = c00 * inv, i01 = c01 * inv, i02 = c02 * inv;
  float i11 = (a * f - c * c) * inv;
  float i12 = (b * c - a * e) * inv;
  float i22 = (a * d - b * b) * inv;
  float p0 = i00 * q0 + i01 * q1 + i02 * q2;
  float p1 = i01 * q0 + i11 * q1 + i12 * q2;
  float p2 = i02 * q0 + i12 * q1 + i22 * q2;
  sP[(size_t)r * 3 + 0] = p0; sP[(size_t)r * 3 + 1] = p1; sP[(size_t)r * 3 + 2] = p2;
  float lt0 = p0 * L[0][0] + p1 * L[1][0] + p2 * L[2][0];
  float lt1 = p0 * L[0][1] + p1 * L[1][1] + p2 * L[2][1];
  float lt2 = p0 * L[0][2] + p1 * L[1][2] + p2 * L[2][2];
  float pp[3] = {p0, p1, p2}, lt[3] = {lt0, lt1, lt2};
  #pragma unroll
  for (int i = 0; i < 3; ++i)
    #pragma unroll
    for (int j = 0; j < 3; ++j) sGL[(size_t)r * 9 + 3 * i + j] = pp[i] * lt[j];
}

__global__ __launch_bounds__(256) void rowB(const float* __restrict__ x,
                                            const float* __restrict__ sGzM,
                                            const float* __restrict__ sGzV,
                                            const float* __restrict__ sGq,
                                            float* __restrict__ out,
                                            float* __restrict__ sDp) {
  int r = blockIdx.x * 256 + threadIdx.x;
  const float* xr = x + (size_t)r * 10;
  float u = xr[9];
  #pragma unroll
  for (int i = 0; i < 3; ++i) {
    float cosq = xr[i], sinq = xr[3 + i], qd = xr[6 + i];
    float dhc = sGzM[(size_t)r * 6 + i] + sGzV[(size_t)r * 6 + i];
    float dhs = sGzM[(size_t)r * 6 + 3 + i] + sGzV[(size_t)r * 6 + 3 + i];
    float F = sGq[(size_t)r * 3 + i] * u;
    float dq = qd;  // dHdp = M_inv @ p = q_dot exactly
    float dp = sinq * dhc - cosq * dhs + F;
    out[(size_t)r * 10 + i]     = -sinq * dq;
    out[(size_t)r * 10 + 3 + i] =  cosq * dq;
    sDp[(size_t)r * 3 + i] = dp;
  }
}

// FROMPART: T summed from the 8 JVP partials; else read precomputed sTL.
template<bool FROMPART>
__global__ __launch_bounds__(256) void rowC(const float* __restrict__ sLvec,
                                            const float* __restrict__ sTL,
                                            const float* __restrict__ Pp,
                                            const float* __restrict__ sP,
                                            const float* __restrict__ sDp,
                                            float* __restrict__ out) {
  int r = blockIdx.x * 256 + threadIdx.x;
  float L[3][3], T[3][3];
  if (FROMPART) {
    float tv[9];
    #pragma unroll
    for (int j = 0; j < 9; ++j) tv[j] = 0.f;
    #pragma unroll
    for (int nt = 0; nt < 8; ++nt) {
      const float* pp = Pp + ((size_t)nt * BS + r) * 9;
      #pragma unroll
      for (int j = 0; j < 9; ++j) tv[j] += pp[j];
    }
    #pragma unroll
    for (int i = 0; i < 3; ++i)
      #pragma unroll
      for (int j = 0; j < 3; ++j) T[i][j] = tv[3 * i + j];
  } else {
    #pragma unroll
    for (int i = 0; i < 3; ++i)
      #pragma unroll
      for (int j = 0; j < 3; ++j) T[i][j] = sTL[(size_t)r * 9 + 3 * i + j];
  }
  #pragma unroll
  for (int i = 0; i < 3; ++i)
    #pragma unroll
    for (int j = 0; j < 3; ++j) L[i][j] = sLvec[(size_t)r * 9 + 3 * i + j];
  float Mi[3][3], dM[3][3];
  #pragma unroll
  for (int i = 0; i < 3; ++i) {
    #pragma unroll
    for (int j = 0; j < 3; ++j) {
      float s = 0.f, sd = 0.f;
      #pragma unroll
      for (int k = 0; k < 3; ++k) {
        s  += L[i][k] * L[j][k];
        sd += T[i][k] * L[j][k] + L[i][k] * T[j][k];
      }
      Mi[i][j] = s + (i == j ? 0.1f : 0.f);
      dM[i][j] = sd;
    }
  }
  float p[3], dp[3];
  #pragma unroll
  for (int i = 0; i < 3; ++i) { p[i] = sP[(size_t)r * 3 + i]; dp[i] = sDp[(size_t)r * 3 + i]; }
  #pragma unroll
  for (int i = 0; i < 3; ++i) {
    float s = 0.f;
    #pragma unroll
    for (int j = 0; j < 3; ++j) s += Mi[i][j] * dp[j] + dM[i][j] * p[j];
    out[(size_t)r * 10 + 6 + i] = s;
  }
  out[(size_t)r * 10 + 9] = 0.f;
}

// ---------------- host
extern "C" void kernel_launch(void* const* d_in, const int* in_sizes, int n_in,
                              void* d_out, int out_size, void* d_ws, size_t ws_size,
                              hipStream_t stream) {
  const float* x   = (const float*)d_in[1];
  const float* MW1 = (const float*)d_in[2];
  const float* Mb1 = (const float*)d_in[3];
  const float* MW2 = (const float*)d_in[4];
  const float* Mb2 = (const float*)d_in[5];
  const float* MW3 = (const float*)d_in[6];
  const float* Mb3 = (const float*)d_in[7];
  const float* VW1 = (const float*)d_in[8];
  const float* Vb1 = (const float*)d_in[9];
  const float* VW2 = (const float*)d_in[10];
  const float* Vb2 = (const float*)d_in[11];
  const float* VW3 = (const float*)d_in[12];
  const float* GW1 = (const float*)d_in[14];
  const float* Gb1 = (const float*)d_in[15];
  const float* GW2 = (const float*)d_in[16];
  const float* Gb2 = (const float*)d_in[17];
  const float* GW3 = (const float*)d_in[18];
  const float* Gb3 = (const float*)d_in[19];
  float* out = (float*)d_out;
  char* ws = (char*)d_ws;

  const size_t PK   = (size_t)HID * HID * 2;
  const size_t BUF  = (size_t)BS * HID * 2;
  const size_t SCAL = (size_t)BS * 48 * 4;
  const size_t NEED = 5 * PK + 3 * BUF + SCAL;
  const size_t PART = (size_t)8 * BS * 9 * 4;        // 9.44 MB partials
  if (ws_size < NEED) return;  // ws too small: fail visibly (output untouched)
  const bool FUSED = (ws_size >= NEED + PART);

  unsigned short* MW2p  = (unsigned short*)(ws + 0 * PK);
  unsigned short* MW2tp = (unsigned short*)(ws + 1 * PK);
  unsigned short* VW2p  = (unsigned short*)(ws + 2 * PK);
  unsigned short* VW2tp = (unsigned short*)(ws + 3 * PK);
  unsigned short* GW2p  = (unsigned short*)(ws + 4 * PK);
  unsigned short* P = (unsigned short*)(ws + 5 * PK);
  unsigned short* Q = (unsigned short*)(ws + 5 * PK + BUF);
  unsigned short* R = (unsigned short*)(ws + 5 * PK + 2 * BUF);
  char* s = ws + 5 * PK + 3 * BUF;
  float* sLvec = (float*)(s);
  float* sP    = (float*)(s + (size_t)BS *  9 * 4);
  float* sGL   = (float*)(s + (size_t)BS * 12 * 4);
  float* sGzM  = (float*)(s + (size_t)BS * 21 * 4);
  float* sGzV  = (float*)(s + (size_t)BS * 27 * 4);
  float* sGq   = (float*)(s + (size_t)BS * 33 * 4);
  float* sDp   = (float*)(s + (size_t)BS * 36 * 4);
  float* sTL   = (float*)(s + (size_t)BS * 39 * 4);
  float* Pp    = (float*)(s + SCAL);                  // partials (fused path)

  dim3 B(256);
  const int G_GEMM = 2048;          // 256 mt x 8 nt
  const int G_EW   = BS * 128 / 256; // 16384
  const int G_SK   = BS / 4;         // 8192
  const int G_ROW  = BS / 256;       // 128

  // weight packing
  pack_w<<<256, B, 0, stream>>>(MW2, MW2p, MW2tp);
  pack_w<<<256, B, 0, stream>>>(VW2, VW2p, VW2tp);
  pack_w<<<256, B, 0, stream>>>(GW2, GW2p, nullptr);

  if (FUSED) {
    // M forward: h2 -> Q (kept), fused red9(MW3) -> partials; rowA collapses
    l1fwd<<<G_EW, B, 0, stream>>>(x, MW1, Mb1, P);                                // h1M
    gemm_bf16<0, 9, false><<<G_GEMM, B, 0, stream>>>(P, MW2p, Q, Mb2, nullptr, nullptr, MW3, Pp);
    rowA<true><<<G_ROW, B, 0, stream>>>(x, sLvec, Pp, Mb3, sP, sGL);              // p, gL (+sLvec)

    // M backward: g2 -> R; g1 fused red6(MW1) -> sGzM (C skipped; aux=P)
    k9bwd<<<G_EW, B, 0, stream>>>(sGL, MW3, Q, R);                                // g2
    gemm_bf16<1, 6, true><<<G_GEMM, B, 0, stream>>>(R, MW2tp, P, nullptr, P, nullptr, MW1, Pp);
    sumP<6><<<BS * 6 / 256, B, 0, stream>>>(Pp, nullptr, sGzM);

    // G forward: h2G fused red3(GW3) -> sGq (+Gb3), C skipped
    l1fwd<<<G_EW, B, 0, stream>>>(x, GW1, Gb1, P);
    gemm_bf16<0, 3, true><<<G_GEMM, B, 0, stream>>>(P, GW2p, R, Gb2, nullptr, nullptr, GW3, Pp);
    sumP<3><<<BS * 3 / 256, B, 0, stream>>>(Pp, Gb3, sGq);

    // V backward: gv2 -> R (fused mapV); gv1 fused red6(VW1) -> sGzV, C skipped
    l1fwd<<<G_EW, B, 0, stream>>>(x, VW1, Vb1, P);                                // vh1
    gemm_bf16<2, 0, false><<<G_GEMM, B, 0, stream>>>(P, VW2p, R, Vb2, nullptr, VW3, nullptr, nullptr);
    gemm_bf16<1, 6, true><<<G_GEMM, B, 0, stream>>>(R, VW2tp, P, nullptr, P, nullptr, VW1, Pp);
    sumP<6><<<BS * 6 / 256, B, 0, stream>>>(Pp, nullptr, sGzV);

    // assemble tangent, dp; write out[:, 0:6]
    rowB<<<G_ROW, B, 0, stream>>>(x, sGzM, sGzV, sGq, out, sDp);

    // JVP: th2 fused red9(MW3) -> partials; rowC collapses (aux = h2 in Q)
    l1t<<<G_EW, B, 0, stream>>>(x, out, MW1, Mb1, P);                             // th1
    gemm_bf16<1, 9, true><<<G_GEMM, B, 0, stream>>>(P, MW2p, R, nullptr, Q, nullptr, MW3, Pp);

    rowC<true><<<G_ROW, B, 0, stream>>>(sLvec, nullptr, Pp, sP, sDp, out);
  } else {
    // fallback: verified R19 sequence
    l1fwd<<<G_EW, B, 0, stream>>>(x, MW1, Mb1, P);                                // h1M
    gemm_bf16<0, 0, false><<<G_GEMM, B, 0, stream>>>(P, MW2p, Q, Mb2, nullptr, nullptr, nullptr, nullptr);
    skinny9<true><<<G_SK, B, 0, stream>>>(Q, MW3, Mb3, sLvec);
    rowA<false><<<G_ROW, B, 0, stream>>>(x, sLvec, nullptr, nullptr, sP, sGL);

    k9bwd<<<G_EW, B, 0, stream>>>(sGL, MW3, Q, R);                                // g2
    gemm_bf16<1, 0, false><<<G_GEMM, B, 0, stream>>>(R, MW2tp, P, nullptr, P, nullptr, nullptr, nullptr);
    skinny6<<<G_SK, B, 0, stream>>>(P, MW1, sGzM);

    l1fwd<<<G_EW, B, 0, stream>>>(x, GW1, Gb1, P);
    gemm_bf16<0, 0, false><<<G_GEMM, B, 0, stream>>>(P, GW2p, R, Gb2, nullptr, nullptr, nullptr, nullptr);
    skinny3<<<G_SK, B, 0, stream>>>(R, GW3, Gb3, sGq);

    l1fwd<<<G_EW, B, 0, stream>>>(x, VW1, Vb1, P);                                // vh1
    gemm_bf16<2, 0, false><<<G_GEMM, B, 0, stream>>>(P, VW2p, R, Vb2, nullptr, VW3, nullptr, nullptr);
    gemm_bf16<1, 0, false><<<G_GEMM, B, 0, stream>>>(R, VW2tp, P, nullptr, P, nullptr, nullptr, nullptr);
    skinny6<<<G_SK, B, 0, stream>>>(P, VW1, sGzV);

    rowB<<<G_ROW, B, 0, stream>>>(x, sGzM, sGzV, sGq, out, sDp);

    l1t<<<G_EW, B, 0, stream>>>(x, out, MW1, Mb1, P);                             // th1
    gemm_bf16<1, 0, false><<<G_GEMM, B, 0, stream>>>(P, MW2p, R, nullptr, Q, nullptr, nullptr, nullptr);
    skinny9<false><<<G_SK, B, 0, stream>>>(R, MW3, nullptr, sTL);

    rowC<false><<<G_ROW, B, 0, stream>>>(sLvec, sTL, nullptr, sP, sDp, out);
  }
}